// Round 1
// baseline (563.221 us; speedup 1.0000x reference)
//
#include <hip/hip_runtime.h>

typedef __attribute__((ext_vector_type(8))) short bf16x8;
typedef __attribute__((ext_vector_type(4))) float f32x4;

static constexpr int M = 8192;       // query rows (b*h*w)
static constexpr int N = 16384;      // feature vectors
static constexpr int K = 512;
static constexpr int BM = 128;
static constexpr int BN = 128;
static constexpr int BK = 64;
static constexpr int NGROUPS = 8;
static constexpr int GROUP_N = N / NGROUPS;   // 2048
static constexpr int NTILES = GROUP_N / BN;   // 16
static constexpr int KCHUNKS = K / BK;        // 8
static constexpr float F_INF = 3.0e38f;

__device__ __forceinline__ unsigned short f2bf(float f) {
    // round-to-nearest-even fp32 -> bf16
    unsigned int u = __float_as_uint(f);
    return (unsigned short)((u + 0x7fffu + ((u >> 16) & 1u)) >> 16);
}

// ---------------- K1: squared norms of all rows ----------------
__global__ void k_norms(const float* __restrict__ Q, const float* __restrict__ F,
                        float* __restrict__ qn, float* __restrict__ fn) {
    int wid = blockIdx.x * 4 + (threadIdx.x >> 6);
    int lane = threadIdx.x & 63;
    const float* src = (wid < M) ? (Q + (size_t)wid * K) : (F + (size_t)(wid - M) * K);
    const float4* p = reinterpret_cast<const float4*>(src) + lane * 2;
    float4 a = p[0], b = p[1];
    float s = a.x*a.x + a.y*a.y + a.z*a.z + a.w*a.w
            + b.x*b.x + b.y*b.y + b.z*b.z + b.w*b.w;
    #pragma unroll
    for (int d = 1; d < 64; d <<= 1) s += __shfl_xor(s, d);
    if (lane == 0) {
        if (wid < M) qn[wid] = s; else fn[wid - M] = s;
    }
}

// ---------------- K2: bf16 MFMA GEMM with fused min+argmin epilogue ----------------
__global__ __launch_bounds__(256, 2)
void k_mingemm(const float* __restrict__ Q, const float* __restrict__ F,
               const float* __restrict__ qn, const float* __restrict__ fn,
               float* __restrict__ pv, unsigned int* __restrict__ pi) {
    __shared__ unsigned short As[BM * BK];   // 16 KiB, XOR-swizzled groups
    __shared__ unsigned short Bs[BN * BK];   // 16 KiB
    __shared__ float qn_t[BM];
    __shared__ float fn_t[BN];

    const int tid = threadIdx.x;
    const int lane = tid & 63;
    const int wave = tid >> 6;
    const int wr = wave >> 1, wc = wave & 1;
    const int l15 = lane & 15, l4 = lane >> 4;

    const int row0 = blockIdx.x * BM;
    const int group = blockIdx.y;
    const int gbase = group * GROUP_N;

    // staging map: 1024 16B-slots, 4 per thread; slot s: row=s>>3, p=s&7
    const int srow = tid >> 3;    // 0..31
    const int p8 = tid & 7;
    const int g8 = p8 ^ (srow & 7);    // logical source group for this physical slot
    const float* pA[4];
    const float* pB[4];
    int dstOff[4];
    #pragma unroll
    for (int i = 0; i < 4; ++i) {
        int r = i * 32 + srow;
        pA[i] = Q + (size_t)(row0 + r) * K + g8 * 8;
        pB[i] = F + (size_t)(gbase + r) * K + g8 * 8;
        dstOff[i] = r * BK + p8 * 8;
    }

    float mval[4][4];
    unsigned int midx[4][4];
    float qnv[4][4];
    #pragma unroll
    for (int a = 0; a < 4; ++a)
        #pragma unroll
        for (int b = 0; b < 4; ++b) { mval[a][b] = F_INF; midx[a][b] = 0; qnv[a][b] = 0.f; }

    for (int nt = 0; nt < NTILES; ++nt) {
        f32x4 acc[4][4];
        #pragma unroll
        for (int a = 0; a < 4; ++a)
            #pragma unroll
            for (int b = 0; b < 4; ++b) acc[a][b] = f32x4{0.f, 0.f, 0.f, 0.f};

        for (int kc = 0; kc < KCHUNKS; ++kc) {
            __syncthreads();   // protect LDS from previous readers
            #pragma unroll
            for (int i = 0; i < 4; ++i) {
                const float4* sa = reinterpret_cast<const float4*>(pA[i] + kc * BK);
                float4 xa = sa[0], ya = sa[1];
                const float4* sb = reinterpret_cast<const float4*>(pB[i] + nt * (BN * K) + kc * BK);
                float4 xb = sb[0], yb = sb[1];
                bf16x8 va, vb;
                va[0]=(short)f2bf(xa.x); va[1]=(short)f2bf(xa.y); va[2]=(short)f2bf(xa.z); va[3]=(short)f2bf(xa.w);
                va[4]=(short)f2bf(ya.x); va[5]=(short)f2bf(ya.y); va[6]=(short)f2bf(ya.z); va[7]=(short)f2bf(ya.w);
                vb[0]=(short)f2bf(xb.x); vb[1]=(short)f2bf(xb.y); vb[2]=(short)f2bf(xb.z); vb[3]=(short)f2bf(xb.w);
                vb[4]=(short)f2bf(yb.x); vb[5]=(short)f2bf(yb.y); vb[6]=(short)f2bf(yb.z); vb[7]=(short)f2bf(yb.w);
                *reinterpret_cast<bf16x8*>(&As[dstOff[i]]) = va;
                *reinterpret_cast<bf16x8*>(&Bs[dstOff[i]]) = vb;
            }
            if (kc == 0) {
                if (nt == 0 && tid < BM) qn_t[tid] = qn[row0 + tid];
                if (tid < BN) fn_t[tid] = fn[gbase + nt * BN + tid];
            }
            __syncthreads();
            if (nt == 0 && kc == 0) {
                #pragma unroll
                for (int fi = 0; fi < 4; ++fi)
                    #pragma unroll
                    for (int j = 0; j < 4; ++j)
                        qnv[fi][j] = qn_t[wr*64 + fi*16 + l4*4 + j];
            }
            #pragma unroll
            for (int ks = 0; ks < 2; ++ks) {
                const int gidx = ks * 4 + l4;
                bf16x8 af[4], bfv[4];
                #pragma unroll
                for (int fi = 0; fi < 4; ++fi) {
                    int r = wr*64 + fi*16 + l15;
                    int pg = gidx ^ (r & 7);
                    af[fi] = *reinterpret_cast<const bf16x8*>(&As[r*BK + pg*8]);
                }
                #pragma unroll
                for (int fj = 0; fj < 4; ++fj) {
                    int r = wc*64 + fj*16 + l15;
                    int pg = gidx ^ (r & 7);
                    bfv[fj] = *reinterpret_cast<const bf16x8*>(&Bs[r*BK + pg*8]);
                }
                #pragma unroll
                for (int fi = 0; fi < 4; ++fi)
                    #pragma unroll
                    for (int fj = 0; fj < 4; ++fj)
                        acc[fi][fj] = __builtin_amdgcn_mfma_f32_16x16x32_bf16(
                            af[fi], bfv[fj], acc[fi][fj], 0, 0, 0);
            }
        }
        // epilogue: d2 = |q|^2 + |f|^2 - 2*dot ; track min+argmin
        const int colb = gbase + nt * BN + wc * 64;
        float fnv[4];
        #pragma unroll
        for (int fj = 0; fj < 4; ++fj) fnv[fj] = fn_t[wc*64 + fj*16 + l15];
        #pragma unroll
        for (int fi = 0; fi < 4; ++fi) {
            #pragma unroll
            for (int j = 0; j < 4; ++j) {
                float qv = qnv[fi][j];
                #pragma unroll
                for (int fj = 0; fj < 4; ++fj) {
                    float d2 = qv + fnv[fj] - 2.0f * acc[fi][fj][j];
                    if (d2 < mval[fi][j]) {
                        mval[fi][j] = d2;
                        midx[fi][j] = (unsigned int)(colb + fj*16 + l15);
                    }
                }
            }
        }
    }
    // cross-lane min over the 16 lanes holding each row, then write partials
    #pragma unroll
    for (int fi = 0; fi < 4; ++fi) {
        #pragma unroll
        for (int j = 0; j < 4; ++j) {
            float v = mval[fi][j];
            unsigned int ix = midx[fi][j];
            #pragma unroll
            for (int d = 1; d < 16; d <<= 1) {
                float ov = __shfl_xor(v, d);
                unsigned int oi = (unsigned int)__shfl_xor((int)ix, d);
                if (ov < v) { v = ov; ix = oi; }
            }
            if (l15 == 0) {
                int rg = row0 + wr*64 + fi*16 + l4*4 + j;
                int pidx = rg * (NGROUPS*2) + group*2 + wc;
                pv[pidx] = v;
                pi[pidx] = ix;
            }
        }
    }
}

// ---------------- K3: merge partials, fp32-refine the min distance ----------------
__global__ void k_refine(const float* __restrict__ Q, const float* __restrict__ F,
                         const float* __restrict__ pv, const unsigned int* __restrict__ pi,
                         float* __restrict__ minD) {
    int row = blockIdx.x * 4 + (threadIdx.x >> 6);
    int lane = threadIdx.x & 63;
    float v = F_INF; unsigned int ix = 0;
    if (lane < 16) { v = pv[row*16 + lane]; ix = pi[row*16 + lane]; }
    #pragma unroll
    for (int d = 1; d < 64; d <<= 1) {
        float ov = __shfl_xor(v, d);
        unsigned int oi = (unsigned int)__shfl_xor((int)ix, d);
        if (ov < v) { v = ov; ix = oi; }
    }
    const float4* q = reinterpret_cast<const float4*>(Q + (size_t)row * K) + lane*2;
    const float4* f = reinterpret_cast<const float4*>(F + (size_t)ix * K) + lane*2;
    float4 a0 = q[0], a1 = q[1], b0 = f[0], b1 = f[1];
    float s = 0.f, dx;
    dx = a0.x-b0.x; s += dx*dx;  dx = a0.y-b0.y; s += dx*dx;
    dx = a0.z-b0.z; s += dx*dx;  dx = a0.w-b0.w; s += dx*dx;
    dx = a1.x-b1.x; s += dx*dx;  dx = a1.y-b1.y; s += dx*dx;
    dx = a1.z-b1.z; s += dx*dx;  dx = a1.w-b1.w; s += dx*dx;
    #pragma unroll
    for (int d = 1; d < 64; d <<= 1) s += __shfl_xor(s, d);
    if (lane == 0) minD[row] = sqrtf(s);
}

// ---------------- K4: per-batch argmax patch (first-index tiebreak) ----------------
__global__ void k_argmax(const float* __restrict__ minD, unsigned int* __restrict__ sel) {
    __shared__ float sv[256];
    __shared__ int si[256];
    int b = blockIdx.x, tid = threadIdx.x;
    float bv = -F_INF; int bi = 0;
    for (int p = tid; p < 1024; p += 256) {
        float v = minD[b*1024 + p];
        if (v > bv) { bv = v; bi = p; }
    }
    sv[tid] = bv; si[tid] = bi;
    __syncthreads();
    for (int s = 128; s > 0; s >>= 1) {
        if (tid < s) {
            if (sv[tid+s] > sv[tid] || (sv[tid+s] == sv[tid] && si[tid+s] < si[tid])) {
                sv[tid] = sv[tid+s]; si[tid] = si[tid+s];
            }
        }
        __syncthreads();
    }
    if (tid == 0) sel[b] = (unsigned int)(b*1024 + si[0]);
}

// ---------------- K5: exact fp32 top-9 (partial per feature-group) for 8 selected rows ----
__global__ void k_top9(const float* __restrict__ Q, const float* __restrict__ F,
                       const unsigned int* __restrict__ sel, float* __restrict__ part9) {
    __shared__ float qs[512];
    __shared__ float dist[2048];
    __shared__ float rv[256];
    __shared__ int ri[256];
    int b = blockIdx.x >> 3, g = blockIdx.x & 7;
    int tid = threadIdx.x;
    unsigned int srow = sel[b];
    if (tid < 128)
        reinterpret_cast<float4*>(qs)[tid] =
            reinterpret_cast<const float4*>(Q + (size_t)srow * K)[tid];
    __syncthreads();
    #pragma unroll
    for (int e = 0; e < 8; ++e) {
        int fl = tid + 256*e;
        const float* fp = F + (size_t)(g*2048 + fl) * K;
        float s = 0.f;
        for (int k = 0; k < 512; k += 4) {
            float4 fv4 = *reinterpret_cast<const float4*>(fp + k);
            float d0 = qs[k]   - fv4.x;
            float d1 = qs[k+1] - fv4.y;
            float d2 = qs[k+2] - fv4.z;
            float d3 = qs[k+3] - fv4.w;
            s += d0*d0 + d1*d1 + d2*d2 + d3*d3;
        }
        dist[fl] = s;
    }
    __syncthreads();
    for (int it = 0; it < 9; ++it) {
        float lv = F_INF; int li = 0;
        #pragma unroll
        for (int e = 0; e < 8; ++e) {
            int idx = tid + 256*e;
            float v = dist[idx];
            if (v < lv) { lv = v; li = idx; }
        }
        rv[tid] = lv; ri[tid] = li;
        __syncthreads();
        for (int s = 128; s > 0; s >>= 1) {
            if (tid < s && rv[tid+s] < rv[tid]) { rv[tid] = rv[tid+s]; ri[tid] = ri[tid+s]; }
            __syncthreads();
        }
        if (tid == 0) {
            part9[(b*8+g)*9 + it] = rv[0];
            dist[ri[0]] = F_INF;
        }
        __syncthreads();
    }
}

// ---------------- K6: merge 8 partial lists per batch, compute exp-weighted score ----------
__global__ void k_final(const float* __restrict__ part9, float* __restrict__ out) {
    int b = threadIdx.x;
    if (b >= 8) return;
    float arr[9];
    #pragma unroll
    for (int i = 0; i < 9; ++i) arr[i] = F_INF;
    for (int g = 0; g < 8; ++g)
        for (int i = 0; i < 9; ++i) {
            float v = part9[(b*8+g)*9 + i];
            #pragma unroll
            for (int s = 0; s < 9; ++s) {
                float lo = fminf(arr[s], v), hi = fmaxf(arr[s], v);
                arr[s] = lo; v = hi;
            }
        }
    float c[9];
    #pragma unroll
    for (int i = 0; i < 9; ++i) c[i] = sqrtf(fmaxf(arr[i], 0.f));
    float c8 = c[8], S = 0.f;
    #pragma unroll
    for (int i = 0; i < 9; ++i) S += expf(c[i] - c8);
    float w = 1.f - 1.f / S;
    out[b] = c[0] * w;
}

// ---------------- K7: combined (blur ∘ bilinear-resize) 256x32 matrix W ----------------
__global__ void k_wmat(float* __restrict__ W) {
    int idx = blockIdx.x * 256 + threadIdx.x;   // 8192
    int o = idx >> 5, j = idx & 31;
    float gsum = 0.f;
    #pragma unroll
    for (int u = 0; u < 33; ++u) { float d = (float)(u - 16); gsum += expf(-d*d * (1.f/32.f)); }
    float acc = 0.f;
    for (int u = 0; u < 33; ++u) {
        float d = (float)(u - 16);
        float gu = expf(-d*d * (1.f/32.f));
        int y = o + u - 16;
        y = y < 0 ? -y : (y > 255 ? 510 - y : y);   // reflect-101
        float xin = ((float)y + 0.5f) * 0.125f - 0.5f;
        float j0f = floorf(xin);
        int j0 = (int)j0f;
        float wfr = xin - j0f;
        float r;
        if (j0 < 0) r = (j == 0) ? 1.f : 0.f;
        else if (j0 >= 31) r = (j == 31) ? 1.f : 0.f;
        else r = (j == j0) ? (1.f - wfr) : ((j == j0 + 1) ? wfr : 0.f);
        acc += gu * r;
    }
    W[idx] = acc / gsum;
}

// ---------------- K8: mask = W * M32 * W^T per batch ----------------
__global__ void k_mask(const float* __restrict__ minD, const float* __restrict__ W,
                       float* __restrict__ outm) {
    __shared__ float Ms[1024];
    __shared__ float Ws[8192];
    __shared__ float Ts[8192];
    int b = blockIdx.x, tid = threadIdx.x;
    for (int i = tid; i < 1024; i += 256) Ms[i] = minD[b*1024 + i];
    for (int i = tid; i < 8192; i += 256) Ws[i] = W[i];
    __syncthreads();
    {   // T[o][j] = sum_i W[o][i] * M[i][j]; thread = o
        int o = tid;
        float wrow[32];
        #pragma unroll
        for (int i = 0; i < 32; ++i) wrow[i] = Ws[o*32 + i];
        for (int j = 0; j < 32; ++j) {
            float s = 0.f;
            #pragma unroll
            for (int i = 0; i < 32; ++i) s += wrow[i] * Ms[i*32 + j];
            Ts[o*32 + j] = s;
        }
    }
    __syncthreads();
    {   // out[o][p] = sum_j T[o][j] * W[p][j]; thread = p (coalesced stores)
        int p = tid;
        float wp[32];
        #pragma unroll
        for (int j = 0; j < 32; ++j) wp[j] = Ws[p*32 + j];
        float* dst = outm + (size_t)b * 65536;
        for (int o = 0; o < 256; ++o) {
            float s = 0.f;
            #pragma unroll
            for (int j = 0; j < 32; ++j) s += Ts[o*32 + j] * wp[j];
            dst[o*256 + p] = s;
        }
    }
}

extern "C" void kernel_launch(void* const* d_in, const int* in_sizes, int n_in,
                              void* d_out, int out_size, void* d_ws, size_t ws_size,
                              hipStream_t stream) {
    const float* Q = (const float*)d_in[0];          // [8192, 512]
    const float* F = (const float*)d_in[1];          // [16384, 512]
    float* out = (float*)d_out;                      // [8] score_out + [8*256*256] mask

    float* ws = (float*)d_ws;                        // ~1.2 MB total
    float* pv = ws;                                  // 8192*16
    unsigned int* pi = (unsigned int*)(pv + 8192*16);// 8192*16
    float* minD = (float*)(pi + 8192*16);            // 8192
    unsigned int* sel = (unsigned int*)(minD + 8192);// 8
    float* part9 = (float*)(sel + 8);                // 8*8*9 = 576
    float* qn = part9 + 576;                         // 8192
    float* fn = qn + 8192;                           // 16384
    float* W  = fn + 16384;                          // 8192

    k_norms <<<dim3((M + N) / 4), 256, 0, stream>>>(Q, F, qn, fn);
    k_wmat  <<<dim3(32),          256, 0, stream>>>(W);
    k_mingemm<<<dim3(M / BM, NGROUPS), 256, 0, stream>>>(Q, F, qn, fn, pv, pi);
    k_refine<<<dim3(M / 4),       256, 0, stream>>>(Q, F, pv, pi, minD);
    k_argmax<<<dim3(8),           256, 0, stream>>>(minD, sel);
    k_top9  <<<dim3(64),          256, 0, stream>>>(Q, F, sel, part9);
    k_final <<<dim3(1),            64, 0, stream>>>(part9, out);
    k_mask  <<<dim3(8),           256, 0, stream>>>(minD, W, out + 8);
}

// Round 2
// 563.039 us; speedup vs baseline: 1.0003x; 1.0003x over previous
//
#include <hip/hip_runtime.h>

typedef __attribute__((ext_vector_type(8))) short bf16x8;
typedef __attribute__((ext_vector_type(4))) float f32x4;

static constexpr int M = 8192;       // query rows (b*h*w)
static constexpr int N = 16384;      // feature vectors
static constexpr int K = 512;
static constexpr int BM = 128;
static constexpr int BN = 128;
static constexpr int BK = 64;
static constexpr int KCHUNKS = K / BK;        // 8
// slow (fallback) path grouping
static constexpr int NGROUPS_S = 8;
static constexpr int GROUP_N_S = N / NGROUPS_S;   // 2048
static constexpr int NTILES_S = GROUP_N_S / BN;   // 16
// fast path grouping
static constexpr int NGROUPS_F = 16;
static constexpr int GROUP_N_F = N / NGROUPS_F;   // 1024
static constexpr int NTILES_F = GROUP_N_F / BN;   // 8
static constexpr float F_INF = 3.0e38f;

__device__ __forceinline__ unsigned short f2bf(float f) {
    // round-to-nearest-even fp32 -> bf16
    unsigned int u = __float_as_uint(f);
    return (unsigned short)((u + 0x7fffu + ((u >> 16) & 1u)) >> 16);
}

__device__ __forceinline__ void gl_lds16(const unsigned short* g, unsigned short* l) {
    __builtin_amdgcn_global_load_lds(
        (const __attribute__((address_space(1))) unsigned int*)g,
        (__attribute__((address_space(3))) unsigned int*)l, 16, 0, 0);
}

// ---------------- K0: pre-cast Q and F to bf16 (RNE) ----------------
__global__ void k_cast(const float* __restrict__ Q, const float* __restrict__ F,
                       unsigned short* __restrict__ Qb, unsigned short* __restrict__ Fb) {
    size_t idx = (size_t)blockIdx.x * 256 + threadIdx.x;   // 8 elems per thread
    const float* src; unsigned short* dst;
    if (idx < (size_t)M * K / 8) { src = Q + idx * 8; dst = Qb + idx * 8; }
    else { size_t e = idx - (size_t)M * K / 8; src = F + e * 8; dst = Fb + e * 8; }
    float4 a = reinterpret_cast<const float4*>(src)[0];
    float4 b = reinterpret_cast<const float4*>(src)[1];
    bf16x8 v;
    v[0]=(short)f2bf(a.x); v[1]=(short)f2bf(a.y); v[2]=(short)f2bf(a.z); v[3]=(short)f2bf(a.w);
    v[4]=(short)f2bf(b.x); v[5]=(short)f2bf(b.y); v[6]=(short)f2bf(b.z); v[7]=(short)f2bf(b.w);
    *reinterpret_cast<bf16x8*>(dst) = v;
}

// ---------------- K1: squared norms of all rows ----------------
__global__ void k_norms(const float* __restrict__ Q, const float* __restrict__ F,
                        float* __restrict__ qn, float* __restrict__ fn) {
    int wid = blockIdx.x * 4 + (threadIdx.x >> 6);
    int lane = threadIdx.x & 63;
    const float* src = (wid < M) ? (Q + (size_t)wid * K) : (F + (size_t)(wid - M) * K);
    const float4* p = reinterpret_cast<const float4*>(src) + lane * 2;
    float4 a = p[0], b = p[1];
    float s = a.x*a.x + a.y*a.y + a.z*a.z + a.w*a.w
            + b.x*b.x + b.y*b.y + b.z*b.z + b.w*b.w;
    #pragma unroll
    for (int d = 1; d < 64; d <<= 1) s += __shfl_xor(s, d);
    if (lane == 0) {
        if (wid < M) qn[wid] = s; else fn[wid - M] = s;
    }
}

// ---------------- K2-fast: bf16 MFMA min-GEMM, global_load_lds staging ----------------
__global__ __launch_bounds__(256, 3)
void k_mingemm_fast(const unsigned short* __restrict__ Qb, const unsigned short* __restrict__ Fb,
                    const float* __restrict__ qn, const float* __restrict__ fn,
                    float* __restrict__ pv, unsigned int* __restrict__ pi) {
    __shared__ unsigned short As[BM * BK];   // 16 KiB, physical slot (r,p) holds logical group p^(r&7)
    __shared__ unsigned short Bs[BN * BK];
    __shared__ float qn_t[BM];
    __shared__ float fn_t[BN];

    const int tid = threadIdx.x;
    const int lane = tid & 63;
    const int wave = tid >> 6;
    const int wr = wave >> 1, wc = wave & 1;
    const int l15 = lane & 15, l4 = lane >> 4;

    const int row0 = blockIdx.x * BM;
    const int gbase = blockIdx.y * GROUP_N_F;

    // staging: each wave issues 4 loads for A, 4 for B; load i covers rows (wave*4+i)*8..+7
    // lane: r_l = lane>>3 (row within 8), p = lane&7 (physical 16B slot)
    // pre-swizzled global source: logical group g = p ^ r_l  (row&7 == r_l)
    const int r_l = lane >> 3, p8 = lane & 7;
    const int g8 = p8 ^ r_l;
    const unsigned short* gA[4];
    const unsigned short* gB[4];
    unsigned short* lA[4];
    unsigned short* lB[4];
    #pragma unroll
    for (int i = 0; i < 4; ++i) {
        int row = (wave * 4 + i) * 8 + r_l;
        gA[i] = Qb + (size_t)(row0 + row) * K + g8 * 8;
        gB[i] = Fb + (size_t)(gbase + row) * K + g8 * 8;
        lA[i] = &As[(wave * 4 + i) * 512];     // wave-uniform base; HW adds lane*16B
        lB[i] = &Bs[(wave * 4 + i) * 512];
    }

    float mval[4][4];
    unsigned int midx[4][4];
    float qnv[4][4];
    #pragma unroll
    for (int a = 0; a < 4; ++a)
        #pragma unroll
        for (int b = 0; b < 4; ++b) { mval[a][b] = F_INF; midx[a][b] = 0; qnv[a][b] = 0.f; }

    for (int nt = 0; nt < NTILES_F; ++nt) {
        f32x4 acc[4][4];
        #pragma unroll
        for (int a = 0; a < 4; ++a)
            #pragma unroll
            for (int b = 0; b < 4; ++b) acc[a][b] = f32x4{0.f, 0.f, 0.f, 0.f};

        const size_t bOff = (size_t)nt * BN * K;
        for (int kc = 0; kc < KCHUNKS; ++kc) {
            __syncthreads();   // protect LDS from previous readers
            #pragma unroll
            for (int i = 0; i < 4; ++i) gl_lds16(gA[i] + kc * BK, lA[i]);
            #pragma unroll
            for (int i = 0; i < 4; ++i) gl_lds16(gB[i] + bOff + kc * BK, lB[i]);
            if (kc == 0) {
                if (nt == 0 && tid < BM) qn_t[tid] = qn[row0 + tid];
                if (tid < BN) fn_t[tid] = fn[gbase + nt * BN + tid];
            }
            __syncthreads();   // compiler drains vmcnt(0) before barrier
            if (nt == 0 && kc == 0) {
                #pragma unroll
                for (int fi = 0; fi < 4; ++fi)
                    #pragma unroll
                    for (int j = 0; j < 4; ++j)
                        qnv[fi][j] = qn_t[wr*64 + fi*16 + l4*4 + j];
            }
            #pragma unroll
            for (int ks = 0; ks < 2; ++ks) {
                const int gidx = ks * 4 + l4;
                bf16x8 af[4], bfv[4];
                #pragma unroll
                for (int fi = 0; fi < 4; ++fi) {
                    int r = wr*64 + fi*16 + l15;
                    int pg = gidx ^ (r & 7);
                    af[fi] = *reinterpret_cast<const bf16x8*>(&As[r*BK + pg*8]);
                }
                #pragma unroll
                for (int fj = 0; fj < 4; ++fj) {
                    int r = wc*64 + fj*16 + l15;
                    int pg = gidx ^ (r & 7);
                    bfv[fj] = *reinterpret_cast<const bf16x8*>(&Bs[r*BK + pg*8]);
                }
                #pragma unroll
                for (int fi = 0; fi < 4; ++fi)
                    #pragma unroll
                    for (int fj = 0; fj < 4; ++fj)
                        acc[fi][fj] = __builtin_amdgcn_mfma_f32_16x16x32_bf16(
                            af[fi], bfv[fj], acc[fi][fj], 0, 0, 0);
            }
        }
        // epilogue: d2 = |q|^2 + |f|^2 - 2*dot ; track min+argmin
        const int colb = gbase + nt * BN + wc * 64;
        float fnv[4];
        #pragma unroll
        for (int fj = 0; fj < 4; ++fj) fnv[fj] = fn_t[wc*64 + fj*16 + l15];
        #pragma unroll
        for (int fi = 0; fi < 4; ++fi) {
            #pragma unroll
            for (int j = 0; j < 4; ++j) {
                float qv = qnv[fi][j];
                #pragma unroll
                for (int fj = 0; fj < 4; ++fj) {
                    float d2 = qv + fnv[fj] - 2.0f * acc[fi][fj][j];
                    if (d2 < mval[fi][j]) {
                        mval[fi][j] = d2;
                        midx[fi][j] = (unsigned int)(colb + fj*16 + l15);
                    }
                }
            }
        }
    }
    #pragma unroll
    for (int fi = 0; fi < 4; ++fi) {
        #pragma unroll
        for (int j = 0; j < 4; ++j) {
            float v = mval[fi][j];
            unsigned int ix = midx[fi][j];
            #pragma unroll
            for (int d = 1; d < 16; d <<= 1) {
                float ov = __shfl_xor(v, d);
                unsigned int oi = (unsigned int)__shfl_xor((int)ix, d);
                if (ov < v) { v = ov; ix = oi; }
            }
            if (l15 == 0) {
                int rg = row0 + wr*64 + fi*16 + l4*4 + j;
                int pidx = rg * 32 + blockIdx.y * 2 + wc;
                pv[pidx] = v;
                pi[pidx] = ix;
            }
        }
    }
}

// ---------------- K2-slow (fallback): in-kernel cast version (R0-proven) ----------------
__global__ __launch_bounds__(256, 2)
void k_mingemm_cast(const float* __restrict__ Q, const float* __restrict__ F,
                    const float* __restrict__ qn, const float* __restrict__ fn,
                    float* __restrict__ pv, unsigned int* __restrict__ pi) {
    __shared__ unsigned short As[BM * BK];
    __shared__ unsigned short Bs[BN * BK];
    __shared__ float qn_t[BM];
    __shared__ float fn_t[BN];

    const int tid = threadIdx.x;
    const int lane = tid & 63;
    const int wave = tid >> 6;
    const int wr = wave >> 1, wc = wave & 1;
    const int l15 = lane & 15, l4 = lane >> 4;

    const int row0 = blockIdx.x * BM;
    const int gbase = blockIdx.y * GROUP_N_S;

    const int srow = tid >> 3;
    const int p8 = tid & 7;
    const int g8 = p8 ^ (srow & 7);
    const float* pA[4];
    const float* pB[4];
    int dstOff[4];
    #pragma unroll
    for (int i = 0; i < 4; ++i) {
        int r = i * 32 + srow;
        pA[i] = Q + (size_t)(row0 + r) * K + g8 * 8;
        pB[i] = F + (size_t)(gbase + r) * K + g8 * 8;
        dstOff[i] = r * BK + p8 * 8;
    }

    float mval[4][4];
    unsigned int midx[4][4];
    float qnv[4][4];
    #pragma unroll
    for (int a = 0; a < 4; ++a)
        #pragma unroll
        for (int b = 0; b < 4; ++b) { mval[a][b] = F_INF; midx[a][b] = 0; qnv[a][b] = 0.f; }

    for (int nt = 0; nt < NTILES_S; ++nt) {
        f32x4 acc[4][4];
        #pragma unroll
        for (int a = 0; a < 4; ++a)
            #pragma unroll
            for (int b = 0; b < 4; ++b) acc[a][b] = f32x4{0.f, 0.f, 0.f, 0.f};

        for (int kc = 0; kc < KCHUNKS; ++kc) {
            __syncthreads();
            #pragma unroll
            for (int i = 0; i < 4; ++i) {
                const float4* sa = reinterpret_cast<const float4*>(pA[i] + kc * BK);
                float4 xa = sa[0], ya = sa[1];
                const float4* sb = reinterpret_cast<const float4*>(pB[i] + nt * (BN * K) + kc * BK);
                float4 xb = sb[0], yb = sb[1];
                bf16x8 va, vb;
                va[0]=(short)f2bf(xa.x); va[1]=(short)f2bf(xa.y); va[2]=(short)f2bf(xa.z); va[3]=(short)f2bf(xa.w);
                va[4]=(short)f2bf(ya.x); va[5]=(short)f2bf(ya.y); va[6]=(short)f2bf(ya.z); va[7]=(short)f2bf(ya.w);
                vb[0]=(short)f2bf(xb.x); vb[1]=(short)f2bf(xb.y); vb[2]=(short)f2bf(xb.z); vb[3]=(short)f2bf(xb.w);
                vb[4]=(short)f2bf(yb.x); vb[5]=(short)f2bf(yb.y); vb[6]=(short)f2bf(yb.z); vb[7]=(short)f2bf(yb.w);
                *reinterpret_cast<bf16x8*>(&As[dstOff[i]]) = va;
                *reinterpret_cast<bf16x8*>(&Bs[dstOff[i]]) = vb;
            }
            if (kc == 0) {
                if (nt == 0 && tid < BM) qn_t[tid] = qn[row0 + tid];
                if (tid < BN) fn_t[tid] = fn[gbase + nt * BN + tid];
            }
            __syncthreads();
            if (nt == 0 && kc == 0) {
                #pragma unroll
                for (int fi = 0; fi < 4; ++fi)
                    #pragma unroll
                    for (int j = 0; j < 4; ++j)
                        qnv[fi][j] = qn_t[wr*64 + fi*16 + l4*4 + j];
            }
            #pragma unroll
            for (int ks = 0; ks < 2; ++ks) {
                const int gidx = ks * 4 + l4;
                bf16x8 af[4], bfv[4];
                #pragma unroll
                for (int fi = 0; fi < 4; ++fi) {
                    int r = wr*64 + fi*16 + l15;
                    int pg = gidx ^ (r & 7);
                    af[fi] = *reinterpret_cast<const bf16x8*>(&As[r*BK + pg*8]);
                }
                #pragma unroll
                for (int fj = 0; fj < 4; ++fj) {
                    int r = wc*64 + fj*16 + l15;
                    int pg = gidx ^ (r & 7);
                    bfv[fj] = *reinterpret_cast<const bf16x8*>(&Bs[r*BK + pg*8]);
                }
                #pragma unroll
                for (int fi = 0; fi < 4; ++fi)
                    #pragma unroll
                    for (int fj = 0; fj < 4; ++fj)
                        acc[fi][fj] = __builtin_amdgcn_mfma_f32_16x16x32_bf16(
                            af[fi], bfv[fj], acc[fi][fj], 0, 0, 0);
            }
        }
        const int colb = gbase + nt * BN + wc * 64;
        float fnv[4];
        #pragma unroll
        for (int fj = 0; fj < 4; ++fj) fnv[fj] = fn_t[wc*64 + fj*16 + l15];
        #pragma unroll
        for (int fi = 0; fi < 4; ++fi) {
            #pragma unroll
            for (int j = 0; j < 4; ++j) {
                float qv = qnv[fi][j];
                #pragma unroll
                for (int fj = 0; fj < 4; ++fj) {
                    float d2 = qv + fnv[fj] - 2.0f * acc[fi][fj][j];
                    if (d2 < mval[fi][j]) {
                        mval[fi][j] = d2;
                        midx[fi][j] = (unsigned int)(colb + fj*16 + l15);
                    }
                }
            }
        }
    }
    #pragma unroll
    for (int fi = 0; fi < 4; ++fi) {
        #pragma unroll
        for (int j = 0; j < 4; ++j) {
            float v = mval[fi][j];
            unsigned int ix = midx[fi][j];
            #pragma unroll
            for (int d = 1; d < 16; d <<= 1) {
                float ov = __shfl_xor(v, d);
                unsigned int oi = (unsigned int)__shfl_xor((int)ix, d);
                if (ov < v) { v = ov; ix = oi; }
            }
            if (l15 == 0) {
                int rg = row0 + wr*64 + fi*16 + l4*4 + j;
                int pidx = rg * 16 + blockIdx.y * 2 + wc;
                pv[pidx] = v;
                pi[pidx] = ix;
            }
        }
    }
}

// ---------------- K3: merge partials, fp32-refine the min distance ----------------
__global__ void k_refine(const float* __restrict__ Q, const float* __restrict__ F,
                         const float* __restrict__ pv, const unsigned int* __restrict__ pi,
                         float* __restrict__ minD, int PS) {
    int row = blockIdx.x * 4 + (threadIdx.x >> 6);
    int lane = threadIdx.x & 63;
    float v = F_INF; unsigned int ix = 0;
    if (lane < PS) { v = pv[row*PS + lane]; ix = pi[row*PS + lane]; }
    #pragma unroll
    for (int d = 1; d < 64; d <<= 1) {
        float ov = __shfl_xor(v, d);
        unsigned int oi = (unsigned int)__shfl_xor((int)ix, d);
        if (ov < v) { v = ov; ix = oi; }
    }
    const float4* q = reinterpret_cast<const float4*>(Q + (size_t)row * K) + lane*2;
    const float4* f = reinterpret_cast<const float4*>(F + (size_t)ix * K) + lane*2;
    float4 a0 = q[0], a1 = q[1], b0 = f[0], b1 = f[1];
    float s = 0.f, dx;
    dx = a0.x-b0.x; s += dx*dx;  dx = a0.y-b0.y; s += dx*dx;
    dx = a0.z-b0.z; s += dx*dx;  dx = a0.w-b0.w; s += dx*dx;
    dx = a1.x-b1.x; s += dx*dx;  dx = a1.y-b1.y; s += dx*dx;
    dx = a1.z-b1.z; s += dx*dx;  dx = a1.w-b1.w; s += dx*dx;
    #pragma unroll
    for (int d = 1; d < 64; d <<= 1) s += __shfl_xor(s, d);
    if (lane == 0) minD[row] = sqrtf(s);
}

// ---------------- K4: per-batch argmax patch (first-index tiebreak) ----------------
__global__ void k_argmax(const float* __restrict__ minD, unsigned int* __restrict__ sel) {
    __shared__ float sv[256];
    __shared__ int si[256];
    int b = blockIdx.x, tid = threadIdx.x;
    float bv = -F_INF; int bi = 0;
    for (int p = tid; p < 1024; p += 256) {
        float v = minD[b*1024 + p];
        if (v > bv) { bv = v; bi = p; }
    }
    sv[tid] = bv; si[tid] = bi;
    __syncthreads();
    for (int s = 128; s > 0; s >>= 1) {
        if (tid < s) {
            if (sv[tid+s] > sv[tid] || (sv[tid+s] == sv[tid] && si[tid+s] < si[tid])) {
                sv[tid] = sv[tid+s]; si[tid] = si[tid+s];
            }
        }
        __syncthreads();
    }
    if (tid == 0) sel[b] = (unsigned int)(b*1024 + si[0]);
}

// ---------------- K5: exact fp32 top-9 (partial per feature-group) for 8 selected rows ----
__global__ void k_top9(const float* __restrict__ Q, const float* __restrict__ F,
                       const unsigned int* __restrict__ sel, float* __restrict__ part9) {
    __shared__ float qs[512];
    __shared__ float dist[2048];
    __shared__ float rv[256];
    __shared__ int ri[256];
    int b = blockIdx.x >> 3, g = blockIdx.x & 7;
    int tid = threadIdx.x;
    unsigned int srow = sel[b];
    if (tid < 128)
        reinterpret_cast<float4*>(qs)[tid] =
            reinterpret_cast<const float4*>(Q + (size_t)srow * K)[tid];
    __syncthreads();
    #pragma unroll
    for (int e = 0; e < 8; ++e) {
        int fl = tid + 256*e;
        const float* fp = F + (size_t)(g*2048 + fl) * K;
        float s = 0.f;
        for (int k = 0; k < 512; k += 4) {
            float4 fv4 = *reinterpret_cast<const float4*>(fp + k);
            float d0 = qs[k]   - fv4.x;
            float d1 = qs[k+1] - fv4.y;
            float d2 = qs[k+2] - fv4.z;
            float d3 = qs[k+3] - fv4.w;
            s += d0*d0 + d1*d1 + d2*d2 + d3*d3;
        }
        dist[fl] = s;
    }
    __syncthreads();
    for (int it = 0; it < 9; ++it) {
        float lv = F_INF; int li = 0;
        #pragma unroll
        for (int e = 0; e < 8; ++e) {
            int idx = tid + 256*e;
            float v = dist[idx];
            if (v < lv) { lv = v; li = idx; }
        }
        rv[tid] = lv; ri[tid] = li;
        __syncthreads();
        for (int s = 128; s > 0; s >>= 1) {
            if (tid < s && rv[tid+s] < rv[tid]) { rv[tid] = rv[tid+s]; ri[tid] = ri[tid+s]; }
            __syncthreads();
        }
        if (tid == 0) {
            part9[(b*8+g)*9 + it] = rv[0];
            dist[ri[0]] = F_INF;
        }
        __syncthreads();
    }
}

// ---------------- K6: merge 8 partial lists per batch, compute exp-weighted score ----------
__global__ void k_final(const float* __restrict__ part9, float* __restrict__ out) {
    int b = threadIdx.x;
    if (b >= 8) return;
    float arr[9];
    #pragma unroll
    for (int i = 0; i < 9; ++i) arr[i] = F_INF;
    for (int g = 0; g < 8; ++g)
        for (int i = 0; i < 9; ++i) {
            float v = part9[(b*8+g)*9 + i];
            #pragma unroll
            for (int s = 0; s < 9; ++s) {
                float lo = fminf(arr[s], v), hi = fmaxf(arr[s], v);
                arr[s] = lo; v = hi;
            }
        }
    float c[9];
    #pragma unroll
    for (int i = 0; i < 9; ++i) c[i] = sqrtf(fmaxf(arr[i], 0.f));
    float c8 = c[8], S = 0.f;
    #pragma unroll
    for (int i = 0; i < 9; ++i) S += expf(c[i] - c8);
    float w = 1.f - 1.f / S;
    out[b] = c[0] * w;
}

// ---------------- K7: combined (blur ∘ bilinear-resize) 256x32 matrix W ----------------
__global__ void k_wmat(float* __restrict__ W) {
    int idx = blockIdx.x * 256 + threadIdx.x;   // 8192
    int o = idx >> 5, j = idx & 31;
    float gsum = 0.f;
    #pragma unroll
    for (int u = 0; u < 33; ++u) { float d = (float)(u - 16); gsum += expf(-d*d * (1.f/32.f)); }
    float acc = 0.f;
    for (int u = 0; u < 33; ++u) {
        float d = (float)(u - 16);
        float gu = expf(-d*d * (1.f/32.f));
        int y = o + u - 16;
        y = y < 0 ? -y : (y > 255 ? 510 - y : y);   // reflect-101
        float xin = ((float)y + 0.5f) * 0.125f - 0.5f;
        float j0f = floorf(xin);
        int j0 = (int)j0f;
        float wfr = xin - j0f;
        float r;
        if (j0 < 0) r = (j == 0) ? 1.f : 0.f;
        else if (j0 >= 31) r = (j == 31) ? 1.f : 0.f;
        else r = (j == j0) ? (1.f - wfr) : ((j == j0 + 1) ? wfr : 0.f);
        acc += gu * r;
    }
    W[idx] = acc / gsum;
}

// ---------------- K8: mask = W * M32 * W^T per batch ----------------
__global__ void k_mask(const float* __restrict__ minD, const float* __restrict__ W,
                       float* __restrict__ outm) {
    __shared__ float Ms[1024];
    __shared__ float Ws[8192];
    __shared__ float Ts[8192];
    int b = blockIdx.x, tid = threadIdx.x;
    for (int i = tid; i < 1024; i += 256) Ms[i] = minD[b*1024 + i];
    for (int i = tid; i < 8192; i += 256) Ws[i] = W[i];
    __syncthreads();
    {
        int o = tid;
        float wrow[32];
        #pragma unroll
        for (int i = 0; i < 32; ++i) wrow[i] = Ws[o*32 + i];
        for (int j = 0; j < 32; ++j) {
            float s = 0.f;
            #pragma unroll
            for (int i = 0; i < 32; ++i) s += wrow[i] * Ms[i*32 + j];
            Ts[o*32 + j] = s;
        }
    }
    __syncthreads();
    {
        int p = tid;
        float wp[32];
        #pragma unroll
        for (int j = 0; j < 32; ++j) wp[j] = Ws[p*32 + j];
        float* dst = outm + (size_t)b * 65536;
        for (int o = 0; o < 256; ++o) {
            float s = 0.f;
            #pragma unroll
            for (int j = 0; j < 32; ++j) s += Ts[o*32 + j] * wp[j];
            dst[o*256 + p] = s;
        }
    }
}

extern "C" void kernel_launch(void* const* d_in, const int* in_sizes, int n_in,
                              void* d_out, int out_size, void* d_ws, size_t ws_size,
                              hipStream_t stream) {
    const float* Q = (const float*)d_in[0];          // [8192, 512]
    const float* F = (const float*)d_in[1];          // [16384, 512]
    float* out = (float*)d_out;                      // [8] score_out + [8*256*256] mask

    // fast path needs: partials (stride 32) + small arrays + Qb (8MB) + Fb (16MB)
    const size_t smallFloats = (size_t)8192*32*2 + 8192 + 8 + 576 + 8192 + 16384 + 8192;
    const size_t REQ = smallFloats*4 + (size_t)M*K*2 + (size_t)N*K*2;
    const bool fast = ws_size >= REQ;
    const int PS = fast ? 32 : 16;

    float* ws = (float*)d_ws;
    float* pv = ws;                                   // 8192*PS
    unsigned int* pi = (unsigned int*)(pv + 8192*PS); // 8192*PS
    float* minD = (float*)(pi + 8192*PS);             // 8192
    unsigned int* sel = (unsigned int*)(minD + 8192); // 8
    float* part9 = (float*)(sel + 8);                 // 576
    float* qn = part9 + 576;                          // 8192
    float* fn = qn + 8192;                            // 16384
    float* W  = fn + 16384;                           // 8192
    unsigned short* Qb = (unsigned short*)(W + 8192); // 8MB (fast only)
    unsigned short* Fb = Qb + (size_t)M*K;            // 16MB (fast only)

    k_norms <<<dim3((M + N) / 4), 256, 0, stream>>>(Q, F, qn, fn);
    k_wmat  <<<dim3(32),          256, 0, stream>>>(W);
    if (fast) {
        k_cast <<<dim3((M + N) * (K/8) / 256), 256, 0, stream>>>(Q, F, Qb, Fb);
        k_mingemm_fast<<<dim3(M / BM, NGROUPS_F), 256, 0, stream>>>(Qb, Fb, qn, fn, pv, pi);
    } else {
        k_mingemm_cast<<<dim3(M / BM, NGROUPS_S), 256, 0, stream>>>(Q, F, qn, fn, pv, pi);
    }
    k_refine<<<dim3(M / 4),       256, 0, stream>>>(Q, F, pv, pi, minD, PS);
    k_argmax<<<dim3(8),           256, 0, stream>>>(minD, sel);
    k_top9  <<<dim3(64),          256, 0, stream>>>(Q, F, sel, part9);
    k_final <<<dim3(1),            64, 0, stream>>>(part9, out);
    k_mask  <<<dim3(8),           256, 0, stream>>>(minD, W, out + 8);
}

// Round 3
// 346.410 us; speedup vs baseline: 1.6259x; 1.6254x over previous
//
#include <hip/hip_runtime.h>

typedef __attribute__((ext_vector_type(8))) short bf16x8;
typedef __attribute__((ext_vector_type(4))) float f32x4;

static constexpr int M = 8192;       // query rows (b*h*w)
static constexpr int N = 16384;      // feature vectors
static constexpr int K = 512;
static constexpr int BM = 128;
static constexpr int BN = 128;
static constexpr int BK = 64;
static constexpr int KCHUNKS = K / BK;        // 8
// slow (fallback) path grouping
static constexpr int NGROUPS_S = 8;
static constexpr int GROUP_N_S = N / NGROUPS_S;   // 2048
static constexpr int NTILES_S = GROUP_N_S / BN;   // 16
// fast path grouping
static constexpr int NGROUPS_F = 16;
static constexpr int GROUP_N_F = N / NGROUPS_F;   // 1024
static constexpr int NTILES_F = GROUP_N_F / BN;   // 8
static constexpr int NCHUNK = NTILES_F * KCHUNKS; // 64 stage-rounds
static constexpr float F_INF = 3.0e38f;

__device__ __forceinline__ unsigned short f2bf(float f) {
    unsigned int u = __float_as_uint(f);
    return (unsigned short)((u + 0x7fffu + ((u >> 16) & 1u)) >> 16);
}

__device__ __forceinline__ void gl_lds16(const unsigned short* g, unsigned short* l) {
    __builtin_amdgcn_global_load_lds(
        (const __attribute__((address_space(1))) unsigned int*)g,
        (__attribute__((address_space(3))) unsigned int*)l, 16, 0, 0);
}

// ---------------- K0: fused cast(Q,F->bf16) + squared norms ----------------
__global__ void k_prep(const float* __restrict__ Q, const float* __restrict__ F,
                       unsigned short* __restrict__ Qb, unsigned short* __restrict__ Fb,
                       float* __restrict__ qn, float* __restrict__ fn) {
    int wid = blockIdx.x * 4 + (threadIdx.x >> 6);
    int lane = threadIdx.x & 63;
    bool isQ = wid < M;
    const float* src = isQ ? (Q + (size_t)wid * K) : (F + (size_t)(wid - M) * K);
    unsigned short* dst = isQ ? (Qb + (size_t)wid * K) : (Fb + (size_t)(wid - M) * K);
    const float4* p = reinterpret_cast<const float4*>(src) + lane * 2;
    float4 a = p[0], b = p[1];
    float s = a.x*a.x + a.y*a.y + a.z*a.z + a.w*a.w
            + b.x*b.x + b.y*b.y + b.z*b.z + b.w*b.w;
    bf16x8 v;
    v[0]=(short)f2bf(a.x); v[1]=(short)f2bf(a.y); v[2]=(short)f2bf(a.z); v[3]=(short)f2bf(a.w);
    v[4]=(short)f2bf(b.x); v[5]=(short)f2bf(b.y); v[6]=(short)f2bf(b.z); v[7]=(short)f2bf(b.w);
    *reinterpret_cast<bf16x8*>(dst + lane * 8) = v;
    #pragma unroll
    for (int d = 1; d < 64; d <<= 1) s += __shfl_xor(s, d);
    if (lane == 0) { if (isQ) qn[wid] = s; else fn[wid - M] = s; }
}

// ---------------- K1 (fallback): squared norms only ----------------
__global__ void k_norms(const float* __restrict__ Q, const float* __restrict__ F,
                        float* __restrict__ qn, float* __restrict__ fn) {
    int wid = blockIdx.x * 4 + (threadIdx.x >> 6);
    int lane = threadIdx.x & 63;
    const float* src = (wid < M) ? (Q + (size_t)wid * K) : (F + (size_t)(wid - M) * K);
    const float4* p = reinterpret_cast<const float4*>(src) + lane * 2;
    float4 a = p[0], b = p[1];
    float s = a.x*a.x + a.y*a.y + a.z*a.z + a.w*a.w
            + b.x*b.x + b.y*b.y + b.z*b.z + b.w*b.w;
    #pragma unroll
    for (int d = 1; d < 64; d <<= 1) s += __shfl_xor(s, d);
    if (lane == 0) { if (wid < M) qn[wid] = s; else fn[wid - M] = s; }
}

// ---------------- K2-fast: dbuf bf16 MFMA min-GEMM, counted-vmcnt pipeline ----------------
__global__ __launch_bounds__(256, 2)
void k_mingemm2(const unsigned short* __restrict__ Qb, const unsigned short* __restrict__ Fb,
                const float* __restrict__ qn, const float* __restrict__ fn,
                float* __restrict__ pv, unsigned int* __restrict__ pi) {
    __shared__ unsigned short As[2][BM * BK];   // 2 x 16 KiB
    __shared__ unsigned short Bs[2][BN * BK];   // 2 x 16 KiB
    __shared__ float qn_t[BM];
    __shared__ float fn_g[GROUP_N_F];           // 4 KiB

    const int tid = threadIdx.x;
    const int lane = tid & 63;
    const int wave = tid >> 6;
    const int wr = wave >> 1, wc = wave & 1;
    const int l15 = lane & 15, l4 = lane >> 4;

    // XCD-chunked bijective swizzle: 1024 wgs, 128 per XCD = 2 full groups
    const int wg = blockIdx.x;
    const int swz = (wg & 7) * 128 + (wg >> 3);
    const int group = swz >> 6;          // 0..15
    const int rowblk = swz & 63;         // 0..63
    const int row0 = rowblk * BM;
    const int gbase = group * GROUP_N_F;

    // staging map (pre-swizzled global source, linear LDS dest):
    const int r_l = lane >> 3, p8 = lane & 7;
    const int g8 = p8 ^ r_l;
    const unsigned short* gA[4];
    const unsigned short* gB[4];
    #pragma unroll
    for (int i = 0; i < 4; ++i) {
        int row = (wave * 4 + i) * 8 + r_l;
        gA[i] = Qb + (size_t)(row0 + row) * K + g8 * 8;
        gB[i] = Fb + (size_t)(gbase + row) * K + g8 * 8;
    }

    auto stage = [&](int ct, int buf) {
        const int kc = ct & 7;
        const size_t bo = (size_t)(ct >> 3) * BN * K;
        #pragma unroll
        for (int i = 0; i < 4; ++i) gl_lds16(gA[i] + kc * BK, &As[buf][(wave * 4 + i) * 512]);
        #pragma unroll
        for (int i = 0; i < 4; ++i) gl_lds16(gB[i] + bo + kc * BK, &Bs[buf][(wave * 4 + i) * 512]);
    };

    // prologue
    for (int i = tid; i < GROUP_N_F; i += 256) fn_g[i] = fn[gbase + i];
    if (tid < BM) qn_t[tid] = qn[row0 + tid];
    stage(0, 0);
    __syncthreads();   // full drain: buf0 + fn_g + qn_t visible

    float qnv[4][4];
    #pragma unroll
    for (int fi = 0; fi < 4; ++fi)
        #pragma unroll
        for (int j = 0; j < 4; ++j)
            qnv[fi][j] = qn_t[wr*64 + fi*16 + l4*4 + j];

    float mval[4][4];
    unsigned int midx[4][4];
    #pragma unroll
    for (int a = 0; a < 4; ++a)
        #pragma unroll
        for (int b = 0; b < 4; ++b) { mval[a][b] = F_INF; midx[a][b] = 0; }

    int cur = 0;
    for (int nt = 0; nt < NTILES_F; ++nt) {
        f32x4 acc[4][4];
        #pragma unroll
        for (int a = 0; a < 4; ++a)
            #pragma unroll
            for (int b = 0; b < 4; ++b) acc[a][b] = f32x4{0.f, 0.f, 0.f, 0.f};

        for (int kc = 0; kc < KCHUNKS; ++kc) {
            const int ct = nt * KCHUNKS + kc;
            if (ct + 1 < NCHUNK) {
                stage(ct + 1, cur ^ 1);                    // 8 loads in flight
                asm volatile("s_waitcnt vmcnt(8)" ::: "memory");   // wait chunk ct only
            } else {
                asm volatile("s_waitcnt vmcnt(0)" ::: "memory");
            }
            __builtin_amdgcn_sched_barrier(0);
            __builtin_amdgcn_s_barrier();                  // all waves: buf[cur] ready
            #pragma unroll
            for (int ks = 0; ks < 2; ++ks) {
                const int gidx = ks * 4 + l4;
                bf16x8 af[4], bfv[4];
                #pragma unroll
                for (int fi = 0; fi < 4; ++fi) {
                    int r = wr*64 + fi*16 + l15;
                    int pg = gidx ^ (r & 7);
                    af[fi] = *reinterpret_cast<const bf16x8*>(&As[cur][r*BK + pg*8]);
                }
                #pragma unroll
                for (int fj = 0; fj < 4; ++fj) {
                    int r = wc*64 + fj*16 + l15;
                    int pg = gidx ^ (r & 7);
                    bfv[fj] = *reinterpret_cast<const bf16x8*>(&Bs[cur][r*BK + pg*8]);
                }
                #pragma unroll
                for (int fi = 0; fi < 4; ++fi)
                    #pragma unroll
                    for (int fj = 0; fj < 4; ++fj)
                        acc[fi][fj] = __builtin_amdgcn_mfma_f32_16x16x32_bf16(
                            af[fi], bfv[fj], acc[fi][fj], 0, 0, 0);
            }
            __builtin_amdgcn_sched_barrier(0);
            __builtin_amdgcn_s_barrier();                  // all waves done reading buf[cur]
            cur ^= 1;
        }
        // epilogue: d2 = |q|^2 + |f|^2 - 2*dot ; track min+argmin (regs + read-only LDS)
        const int colb = gbase + nt * BN + wc * 64;
        float fnv[4];
        #pragma unroll
        for (int fj = 0; fj < 4; ++fj) fnv[fj] = fn_g[nt*BN + wc*64 + fj*16 + l15];
        #pragma unroll
        for (int fi = 0; fi < 4; ++fi) {
            #pragma unroll
            for (int j = 0; j < 4; ++j) {
                float qv = qnv[fi][j];
                #pragma unroll
                for (int fj = 0; fj < 4; ++fj) {
                    float d2 = qv + fnv[fj] - 2.0f * acc[fi][fj][j];
                    if (d2 < mval[fi][j]) {
                        mval[fi][j] = d2;
                        midx[fi][j] = (unsigned int)(colb + fj*16 + l15);
                    }
                }
            }
        }
    }
    #pragma unroll
    for (int fi = 0; fi < 4; ++fi) {
        #pragma unroll
        for (int j = 0; j < 4; ++j) {
            float v = mval[fi][j];
            unsigned int ix = midx[fi][j];
            #pragma unroll
            for (int d = 1; d < 16; d <<= 1) {
                float ov = __shfl_xor(v, d);
                unsigned int oi = (unsigned int)__shfl_xor((int)ix, d);
                if (ov < v) { v = ov; ix = oi; }
            }
            if (l15 == 0) {
                int rg = row0 + wr*64 + fi*16 + l4*4 + j;
                int pidx = rg * 32 + group*2 + wc;
                pv[pidx] = v;
                pi[pidx] = ix;
            }
        }
    }
}

// ---------------- K2-slow (fallback): in-kernel cast version (R0-proven) ----------------
__global__ __launch_bounds__(256, 2)
void k_mingemm_cast(const float* __restrict__ Q, const float* __restrict__ F,
                    const float* __restrict__ qn, const float* __restrict__ fn,
                    float* __restrict__ pv, unsigned int* __restrict__ pi) {
    __shared__ unsigned short As[BM * BK];
    __shared__ unsigned short Bs[BN * BK];
    __shared__ float qn_t[BM];
    __shared__ float fn_t[BN];

    const int tid = threadIdx.x;
    const int lane = tid & 63;
    const int wave = tid >> 6;
    const int wr = wave >> 1, wc = wave & 1;
    const int l15 = lane & 15, l4 = lane >> 4;

    const int row0 = blockIdx.x * BM;
    const int gbase = blockIdx.y * GROUP_N_S;

    const int srow = tid >> 3;
    const int p8 = tid & 7;
    const int g8 = p8 ^ (srow & 7);
    const float* pA[4];
    const float* pB[4];
    int dstOff[4];
    #pragma unroll
    for (int i = 0; i < 4; ++i) {
        int r = i * 32 + srow;
        pA[i] = Q + (size_t)(row0 + r) * K + g8 * 8;
        pB[i] = F + (size_t)(gbase + r) * K + g8 * 8;
        dstOff[i] = r * BK + p8 * 8;
    }

    float mval[4][4];
    unsigned int midx[4][4];
    float qnv[4][4];
    #pragma unroll
    for (int a = 0; a < 4; ++a)
        #pragma unroll
        for (int b = 0; b < 4; ++b) { mval[a][b] = F_INF; midx[a][b] = 0; qnv[a][b] = 0.f; }

    for (int nt = 0; nt < NTILES_S; ++nt) {
        f32x4 acc[4][4];
        #pragma unroll
        for (int a = 0; a < 4; ++a)
            #pragma unroll
            for (int b = 0; b < 4; ++b) acc[a][b] = f32x4{0.f, 0.f, 0.f, 0.f};

        for (int kc = 0; kc < KCHUNKS; ++kc) {
            __syncthreads();
            #pragma unroll
            for (int i = 0; i < 4; ++i) {
                const float4* sa = reinterpret_cast<const float4*>(pA[i] + kc * BK);
                float4 xa = sa[0], ya = sa[1];
                const float4* sb = reinterpret_cast<const float4*>(pB[i] + nt * (BN * K) + kc * BK);
                float4 xb = sb[0], yb = sb[1];
                bf16x8 va, vb;
                va[0]=(short)f2bf(xa.x); va[1]=(short)f2bf(xa.y); va[2]=(short)f2bf(xa.z); va[3]=(short)f2bf(xa.w);
                va[4]=(short)f2bf(ya.x); va[5]=(short)f2bf(ya.y); va[6]=(short)f2bf(ya.z); va[7]=(short)f2bf(ya.w);
                vb[0]=(short)f2bf(xb.x); vb[1]=(short)f2bf(xb.y); vb[2]=(short)f2bf(xb.z); vb[3]=(short)f2bf(xb.w);
                vb[4]=(short)f2bf(yb.x); vb[5]=(short)f2bf(yb.y); vb[6]=(short)f2bf(yb.z); vb[7]=(short)f2bf(yb.w);
                *reinterpret_cast<bf16x8*>(&As[dstOff[i]]) = va;
                *reinterpret_cast<bf16x8*>(&Bs[dstOff[i]]) = vb;
            }
            if (kc == 0) {
                if (nt == 0 && tid < BM) qn_t[tid] = qn[row0 + tid];
                if (tid < BN) fn_t[tid] = fn[gbase + nt * BN + tid];
            }
            __syncthreads();
            if (nt == 0 && kc == 0) {
                #pragma unroll
                for (int fi = 0; fi < 4; ++fi)
                    #pragma unroll
                    for (int j = 0; j < 4; ++j)
                        qnv[fi][j] = qn_t[wr*64 + fi*16 + l4*4 + j];
            }
            #pragma unroll
            for (int ks = 0; ks < 2; ++ks) {
                const int gidx = ks * 4 + l4;
                bf16x8 af[4], bfv[4];
                #pragma unroll
                for (int fi = 0; fi < 4; ++fi) {
                    int r = wr*64 + fi*16 + l15;
                    int pg = gidx ^ (r & 7);
                    af[fi] = *reinterpret_cast<const bf16x8*>(&As[r*BK + pg*8]);
                }
                #pragma unroll
                for (int fj = 0; fj < 4; ++fj) {
                    int r = wc*64 + fj*16 + l15;
                    int pg = gidx ^ (r & 7);
                    bfv[fj] = *reinterpret_cast<const bf16x8*>(&Bs[r*BK + pg*8]);
                }
                #pragma unroll
                for (int fi = 0; fi < 4; ++fi)
                    #pragma unroll
                    for (int fj = 0; fj < 4; ++fj)
                        acc[fi][fj] = __builtin_amdgcn_mfma_f32_16x16x32_bf16(
                            af[fi], bfv[fj], acc[fi][fj], 0, 0, 0);
            }
        }
        const int colb = gbase + nt * BN + wc * 64;
        float fnv[4];
        #pragma unroll
        for (int fj = 0; fj < 4; ++fj) fnv[fj] = fn_t[wc*64 + fj*16 + l15];
        #pragma unroll
        for (int fi = 0; fi < 4; ++fi) {
            #pragma unroll
            for (int j = 0; j < 4; ++j) {
                float qv = qnv[fi][j];
                #pragma unroll
                for (int fj = 0; fj < 4; ++fj) {
                    float d2 = qv + fnv[fj] - 2.0f * acc[fi][fj][j];
                    if (d2 < mval[fi][j]) {
                        mval[fi][j] = d2;
                        midx[fi][j] = (unsigned int)(colb + fj*16 + l15);
                    }
                }
            }
        }
    }
    #pragma unroll
    for (int fi = 0; fi < 4; ++fi) {
        #pragma unroll
        for (int j = 0; j < 4; ++j) {
            float v = mval[fi][j];
            unsigned int ix = midx[fi][j];
            #pragma unroll
            for (int d = 1; d < 16; d <<= 1) {
                float ov = __shfl_xor(v, d);
                unsigned int oi = (unsigned int)__shfl_xor((int)ix, d);
                if (ov < v) { v = ov; ix = oi; }
            }
            if (l15 == 0) {
                int rg = row0 + wr*64 + fi*16 + l4*4 + j;
                int pidx = rg * 16 + blockIdx.y * 2 + wc;
                pv[pidx] = v;
                pi[pidx] = ix;
            }
        }
    }
}

// ---------------- K3: merge partials, fp32-refine the min distance ----------------
__global__ void k_refine(const float* __restrict__ Q, const float* __restrict__ F,
                         const float* __restrict__ pv, const unsigned int* __restrict__ pi,
                         float* __restrict__ minD, int PS) {
    int row = blockIdx.x * 4 + (threadIdx.x >> 6);
    int lane = threadIdx.x & 63;
    float v = F_INF; unsigned int ix = 0;
    if (lane < PS) { v = pv[row*PS + lane]; ix = pi[row*PS + lane]; }
    #pragma unroll
    for (int d = 1; d < 64; d <<= 1) {
        float ov = __shfl_xor(v, d);
        unsigned int oi = (unsigned int)__shfl_xor((int)ix, d);
        if (ov < v) { v = ov; ix = oi; }
    }
    const float4* q = reinterpret_cast<const float4*>(Q + (size_t)row * K) + lane*2;
    const float4* f = reinterpret_cast<const float4*>(F + (size_t)ix * K) + lane*2;
    float4 a0 = q[0], a1 = q[1], b0 = f[0], b1 = f[1];
    float s = 0.f, dx;
    dx = a0.x-b0.x; s += dx*dx;  dx = a0.y-b0.y; s += dx*dx;
    dx = a0.z-b0.z; s += dx*dx;  dx = a0.w-b0.w; s += dx*dx;
    dx = a1.x-b1.x; s += dx*dx;  dx = a1.y-b1.y; s += dx*dx;
    dx = a1.z-b1.z; s += dx*dx;  dx = a1.w-b1.w; s += dx*dx;
    #pragma unroll
    for (int d = 1; d < 64; d <<= 1) s += __shfl_xor(s, d);
    if (lane == 0) minD[row] = sqrtf(s);
}

// ---------------- K4: per-batch argmax patch (first-index tiebreak) ----------------
__global__ void k_argmax(const float* __restrict__ minD, unsigned int* __restrict__ sel) {
    __shared__ float sv[256];
    __shared__ int si[256];
    int b = blockIdx.x, tid = threadIdx.x;
    float bv = -F_INF; int bi = 0;
    for (int p = tid; p < 1024; p += 256) {
        float v = minD[b*1024 + p];
        if (v > bv) { bv = v; bi = p; }
    }
    sv[tid] = bv; si[tid] = bi;
    __syncthreads();
    for (int s = 128; s > 0; s >>= 1) {
        if (tid < s) {
            if (sv[tid+s] > sv[tid] || (sv[tid+s] == sv[tid] && si[tid+s] < si[tid])) {
                sv[tid] = sv[tid+s]; si[tid] = si[tid+s];
            }
        }
        __syncthreads();
    }
    if (tid == 0) sel[b] = (unsigned int)(b*1024 + si[0]);
}

// ---------------- K5-fast: distances from 8 selected rows to all F (read F once) --------
__global__ void k_dist8(const float* __restrict__ Q, const float* __restrict__ F,
                        const unsigned int* __restrict__ sel, float* __restrict__ d2all) {
    __shared__ float qs[8][512];   // 16 KiB
    int tid = threadIdx.x;
    int lane = tid & 63, wave = tid >> 6;
    for (int i = tid; i < 8*512; i += 256) {
        int b = i >> 9;
        qs[b][i & 511] = Q[(size_t)sel[b] * K + (i & 511)];
    }
    __syncthreads();
    int base = blockIdx.x * 128 + wave * 32;
    for (int r = 0; r < 32; ++r) {
        int row = base + r;
        const float4* fp = reinterpret_cast<const float4*>(F + (size_t)row * K) + lane*2;
        float4 f0 = fp[0], f1 = fp[1];
        float fv[8] = {f0.x,f0.y,f0.z,f0.w,f1.x,f1.y,f1.z,f1.w};
        float accb[8];
        #pragma unroll
        for (int b = 0; b < 8; ++b) {
            float s = 0.f;
            #pragma unroll
            for (int e = 0; e < 8; ++e) {
                float d = fv[e] - qs[b][lane*8 + e];
                s += d * d;
            }
            accb[b] = s;
        }
        #pragma unroll
        for (int d = 1; d < 64; d <<= 1)
            #pragma unroll
            for (int b = 0; b < 8; ++b) accb[b] += __shfl_xor(accb[b], d);
        if (lane == 0) {
            #pragma unroll
            for (int b = 0; b < 8; ++b) d2all[b * N + row] = accb[b];
        }
    }
}

// ---------------- K6-fast: per-batch 9-smallest + score (parallel merge) ----------------
__global__ void k_sel9(const float* __restrict__ d2all, float* __restrict__ out) {
    __shared__ float sv[256 * 10];
    int b = blockIdx.x, tid = threadIdx.x;
    float v[9];
    #pragma unroll
    for (int i = 0; i < 9; ++i) v[i] = F_INF;
    for (int i = tid; i < N; i += 256) {
        float x = d2all[b * N + i];
        #pragma unroll
        for (int s = 0; s < 9; ++s) {
            float lo = fminf(v[s], x), hi = fmaxf(v[s], x);
            v[s] = lo; x = hi;
        }
    }
    #pragma unroll
    for (int i = 0; i < 9; ++i) sv[tid*10 + i] = v[i];
    sv[tid*10 + 9] = F_INF;
    __syncthreads();
    for (int s = 128; s > 0; s >>= 1) {
        if (tid < s) {
            int ia = 1, ib = 1;
            float av = sv[tid*10], bv = sv[(tid+s)*10];
            float c[9];
            #pragma unroll
            for (int k = 0; k < 9; ++k) {
                bool ta = av <= bv;
                c[k] = ta ? av : bv;
                float na = sv[tid*10 + ia], nb = sv[(tid+s)*10 + ib];
                if (ta) { av = na; ++ia; } else { bv = nb; ++ib; }
            }
            #pragma unroll
            for (int k = 0; k < 9; ++k) sv[tid*10 + k] = c[k];
        }
        __syncthreads();
    }
    if (tid == 0) {
        float c[9];
        #pragma unroll
        for (int i = 0; i < 9; ++i) c[i] = sqrtf(fmaxf(sv[i], 0.f));
        float S = 0.f;
        #pragma unroll
        for (int i = 0; i < 9; ++i) S += expf(c[i] - c[8]);
        out[b] = c[0] * (1.f - 1.f / S);
    }
}

// ---------------- K5-slow / K6-slow (fallback, R1-proven) ----------------
__global__ void k_top9(const float* __restrict__ Q, const float* __restrict__ F,
                       const unsigned int* __restrict__ sel, float* __restrict__ part9) {
    __shared__ float qs[512];
    __shared__ float dist[2048];
    __shared__ float rv[256];
    __shared__ int ri[256];
    int b = blockIdx.x >> 3, g = blockIdx.x & 7;
    int tid = threadIdx.x;
    unsigned int srow = sel[b];
    if (tid < 128)
        reinterpret_cast<float4*>(qs)[tid] =
            reinterpret_cast<const float4*>(Q + (size_t)srow * K)[tid];
    __syncthreads();
    #pragma unroll
    for (int e = 0; e < 8; ++e) {
        int fl = tid + 256*e;
        const float* fp = F + (size_t)(g*2048 + fl) * K;
        float s = 0.f;
        for (int k = 0; k < 512; k += 4) {
            float4 fv4 = *reinterpret_cast<const float4*>(fp + k);
            float d0 = qs[k]   - fv4.x;
            float d1 = qs[k+1] - fv4.y;
            float d2 = qs[k+2] - fv4.z;
            float d3 = qs[k+3] - fv4.w;
            s += d0*d0 + d1*d1 + d2*d2 + d3*d3;
        }
        dist[fl] = s;
    }
    __syncthreads();
    for (int it = 0; it < 9; ++it) {
        float lv = F_INF; int li = 0;
        #pragma unroll
        for (int e = 0; e < 8; ++e) {
            int idx = tid + 256*e;
            float v = dist[idx];
            if (v < lv) { lv = v; li = idx; }
        }
        rv[tid] = lv; ri[tid] = li;
        __syncthreads();
        for (int s = 128; s > 0; s >>= 1) {
            if (tid < s && rv[tid+s] < rv[tid]) { rv[tid] = rv[tid+s]; ri[tid] = ri[tid+s]; }
            __syncthreads();
        }
        if (tid == 0) {
            part9[(b*8+g)*9 + it] = rv[0];
            dist[ri[0]] = F_INF;
        }
        __syncthreads();
    }
}

__global__ void k_final(const float* __restrict__ part9, float* __restrict__ out) {
    int b = threadIdx.x;
    if (b >= 8) return;
    float arr[9];
    #pragma unroll
    for (int i = 0; i < 9; ++i) arr[i] = F_INF;
    for (int g = 0; g < 8; ++g)
        for (int i = 0; i < 9; ++i) {
            float v = part9[(b*8+g)*9 + i];
            #pragma unroll
            for (int s = 0; s < 9; ++s) {
                float lo = fminf(arr[s], v), hi = fmaxf(arr[s], v);
                arr[s] = lo; v = hi;
            }
        }
    float c[9];
    #pragma unroll
    for (int i = 0; i < 9; ++i) c[i] = sqrtf(fmaxf(arr[i], 0.f));
    float c8 = c[8], S = 0.f;
    #pragma unroll
    for (int i = 0; i < 9; ++i) S += expf(c[i] - c8);
    float w = 1.f - 1.f / S;
    out[b] = c[0] * w;
}

// ---------------- K7: combined (blur ∘ bilinear-resize) 256x32 matrix W ----------------
__global__ void k_wmat(float* __restrict__ W) {
    int idx = blockIdx.x * 256 + threadIdx.x;   // 8192
    int o = idx >> 5, j = idx & 31;
    float gsum = 0.f;
    #pragma unroll
    for (int u = 0; u < 33; ++u) { float d = (float)(u - 16); gsum += expf(-d*d * (1.f/32.f)); }
    float acc = 0.f;
    for (int u = 0; u < 33; ++u) {
        float d = (float)(u - 16);
        float gu = expf(-d*d * (1.f/32.f));
        int y = o + u - 16;
        y = y < 0 ? -y : (y > 255 ? 510 - y : y);   // reflect-101
        float xin = ((float)y + 0.5f) * 0.125f - 0.5f;
        float j0f = floorf(xin);
        int j0 = (int)j0f;
        float wfr = xin - j0f;
        float r;
        if (j0 < 0) r = (j == 0) ? 1.f : 0.f;
        else if (j0 >= 31) r = (j == 31) ? 1.f : 0.f;
        else r = (j == j0) ? (1.f - wfr) : ((j == j0 + 1) ? wfr : 0.f);
        acc += gu * r;
    }
    W[idx] = acc / gsum;
}

// ---------------- K8: mask = W * M32 * W^T per batch ----------------
__global__ void k_mask(const float* __restrict__ minD, const float* __restrict__ W,
                       float* __restrict__ outm) {
    __shared__ float Ms[1024];
    __shared__ float Ws[8192];
    __shared__ float Ts[8192];
    int b = blockIdx.x, tid = threadIdx.x;
    for (int i = tid; i < 1024; i += 256) Ms[i] = minD[b*1024 + i];
    for (int i = tid; i < 8192; i += 256) Ws[i] = W[i];
    __syncthreads();
    {
        int o = tid;
        float wrow[32];
        #pragma unroll
        for (int i = 0; i < 32; ++i) wrow[i] = Ws[o*32 + i];
        for (int j = 0; j < 32; ++j) {
            float s = 0.f;
            #pragma unroll
            for (int i = 0; i < 32; ++i) s += wrow[i] * Ms[i*32 + j];
            Ts[o*32 + j] = s;
        }
    }
    __syncthreads();
    {
        int p = tid;
        float wp[32];
        #pragma unroll
        for (int j = 0; j < 32; ++j) wp[j] = Ws[p*32 + j];
        float* dst = outm + (size_t)b * 65536;
        for (int o = 0; o < 256; ++o) {
            float s = 0.f;
            #pragma unroll
            for (int j = 0; j < 32; ++j) s += Ts[o*32 + j] * wp[j];
            dst[o*256 + p] = s;
        }
    }
}

extern "C" void kernel_launch(void* const* d_in, const int* in_sizes, int n_in,
                              void* d_out, int out_size, void* d_ws, size_t ws_size,
                              hipStream_t stream) {
    const float* Q = (const float*)d_in[0];          // [8192, 512]
    const float* F = (const float*)d_in[1];          // [16384, 512]
    float* out = (float*)d_out;                      // [8] score_out + [8*256*256] mask

    const size_t smallFloats = (size_t)8192*32*2 + 8192 + 8 + 576 + (size_t)8*N + 8192 + 16384 + 8192;
    const size_t REQ = smallFloats*4 + (size_t)M*K*2 + (size_t)N*K*2;
    const bool fast = ws_size >= REQ;
    const int PS = fast ? 32 : 16;

    float* ws = (float*)d_ws;
    float* pv = ws;                                    // 8192*PS
    unsigned int* pi = (unsigned int*)(pv + 8192*PS);  // 8192*PS
    float* minD = (float*)(pi + 8192*PS);              // 8192
    unsigned int* sel = (unsigned int*)(minD + 8192);  // 8
    float* part9 = (float*)(sel + 8);                  // 576
    float* d2all = part9 + 576;                        // 8*16384 (fast only)
    float* qn = d2all + (size_t)8*N;                   // 8192
    float* fn = qn + 8192;                             // 16384
    float* W  = fn + 16384;                            // 8192
    unsigned short* Qb = (unsigned short*)(W + 8192);  // 8MB (fast only)
    unsigned short* Fb = Qb + (size_t)M*K;             // 16MB (fast only)

    k_wmat <<<dim3(32), 256, 0, stream>>>(W);
    if (fast) {
        k_prep <<<dim3((M + N) / 4), 256, 0, stream>>>(Q, F, Qb, Fb, qn, fn);
        k_mingemm2<<<dim3(M / BM * NGROUPS_F), 256, 0, stream>>>(Qb, Fb, qn, fn, pv, pi);
        k_refine<<<dim3(M / 4), 256, 0, stream>>>(Q, F, pv, pi, minD, PS);
        k_argmax<<<dim3(8), 256, 0, stream>>>(minD, sel);
        k_dist8<<<dim3(N / 128), 256, 0, stream>>>(Q, F, sel, d2all);
        k_sel9 <<<dim3(8), 256, 0, stream>>>(d2all, out);
    } else {
        k_norms<<<dim3((M + N) / 4), 256, 0, stream>>>(Q, F, qn, fn);
        k_mingemm_cast<<<dim3(M / BM, NGROUPS_S), 256, 0, stream>>>(Q, F, qn, fn, pv, pi);
        k_refine<<<dim3(M / 4), 256, 0, stream>>>(Q, F, pv, pi, minD, PS);
        k_argmax<<<dim3(8), 256, 0, stream>>>(minD, sel);
        k_top9 <<<dim3(64), 256, 0, stream>>>(Q, F, sel, part9);
        k_final<<<dim3(1), 64, 0, stream>>>(part9, out);
    }
    k_mask <<<dim3(8), 256, 0, stream>>>(minD, W, out + 8);
}